// Round 8
// baseline (560.432 us; speedup 1.0000x reference)
//
#include <hip/hip_runtime.h>
#include <hip/hip_bf16.h>

// ---------------------------------------------------------------------------
// EdgeClassifier: 2x GCNConv + edge MLP. All node intermediates bf16.
//   CSR build -> nodemm32(MFMA) -> agg -> nodemm64(MFMA) -> agg
//   -> persistent-block all-MFMA edge MLP:
//      * weights staged ONCE per block into LDS as per-lane register image
//      * node rows cooperatively gathered (full 64B lines) into per-wave LDS
//        slab (stride 144B, slot-uniform), frags re-read linearly
//      * hid aliases the slab; no barriers in the tile loop
//      * edge-order processing (coalesced stores)
// ---------------------------------------------------------------------------

typedef __attribute__((ext_vector_type(8))) short  bf16x8;
typedef __attribute__((ext_vector_type(16))) float f32x16;

__device__ inline short f2bf(float f)
{
    union { float f; unsigned u; } v; v.f = f;
    unsigned r = v.u + 0x7fff + ((v.u >> 16) & 1);   // RNE
    return (short)(r >> 16);
}

__device__ inline float2 bfp2f(unsigned u)
{
    union { unsigned u; float f; } a, b;
    a.u = u << 16;
    b.u = u & 0xffff0000u;
    return make_float2(a.f, b.f);
}

// ---------------- CSR build ----------------
__global__ __launch_bounds__(256) void k_hist(const int* __restrict__ ei, int* __restrict__ degcnt, int E)
{
    int e = blockIdx.x * 256 + threadIdx.x;
    if (e < E) atomicAdd(&degcnt[ei[E + e]], 1);
}

__global__ __launch_bounds__(256) void k_dinv_bsum(const int* __restrict__ degcnt, float* __restrict__ dinv,
                                                   int n, int* __restrict__ bsum)
{
    __shared__ int s[256];
    int t = threadIdx.x;
    int i = blockIdx.x * 256 + t;
    int dg = (i < n) ? degcnt[i] : 0;
    if (i < n) dinv[i] = rsqrtf((float)(dg + 1));
    s[t] = dg;
    __syncthreads();
    for (int o = 128; o > 0; o >>= 1) {
        if (t < o) s[t] += s[t + o];
        __syncthreads();
    }
    if (t == 0) bsum[blockIdx.x] = s[0];
}

__global__ __launch_bounds__(512) void k_boff(const int* __restrict__ bsum, int nb, int* __restrict__ boff)
{
    __shared__ int s[512];
    int t = threadIdx.x;
    int v = (t < nb) ? bsum[t] : 0;
    s[t] = v;
    __syncthreads();
    for (int o = 1; o < 512; o <<= 1) {
        int a = (t >= o) ? s[t - o] : 0;
        __syncthreads();
        s[t] += a;
        __syncthreads();
    }
    if (t < nb) boff[t] = s[t] - v;
}

__global__ __launch_bounds__(256) void k_rowstart(const int* __restrict__ deg, const int* __restrict__ boff,
                                                  int* __restrict__ rs, int n, int total)
{
    __shared__ int s[256];
    int t = threadIdx.x;
    int i = blockIdx.x * 256 + t;
    int v = (i < n) ? deg[i] : 0;
    s[t] = v;
    __syncthreads();
    for (int o = 1; o < 256; o <<= 1) {
        int a = (t >= o) ? s[t - o] : 0;
        __syncthreads();
        s[t] += a;
        __syncthreads();
    }
    if (i < n) rs[i] = boff[blockIdx.x] + s[t] - v;
    if (i == 0) rs[n] = total;
}

__global__ __launch_bounds__(256) void k_scatter(const int* __restrict__ ei, const int* __restrict__ rs,
                                                 int* __restrict__ cursor, int* __restrict__ col, int E)
{
    int e = blockIdx.x * 256 + threadIdx.x;
    if (e < E) {
        int d = ei[E + e];
        int pos = atomicAdd(&cursor[d], 1);
        col[rs[d] + pos] = ei[e];
    }
}

// ---------------- weight prep (all bf16, transposed) ----------------
// Wc1T[64][144] | Wc2T[32][64] (class-padded) | W2T[64][64] | W1T[64][32]
__global__ __launch_bounds__(256) void k_prep(const float* __restrict__ Wc1, const float* __restrict__ Wc2,
                                              const float* __restrict__ W2, const float* __restrict__ W1,
                                              short* __restrict__ Wc1T, short* __restrict__ Wc2T,
                                              short* __restrict__ W2T, short* __restrict__ W1T)
{
    int t = blockIdx.x * 256 + threadIdx.x;
    if (t < 9216) {
        int j = t / 144, k = t - j * 144;
        Wc1T[t] = f2bf(Wc1[k * 64 + j]);
    } else if (t < 11264) {
        int u = t - 9216;
        int rr = u / 64, k = u - rr * 64;
        Wc2T[u] = (rr < 5) ? f2bf(Wc2[k * 5 + rr]) : (short)0;
    } else if (t < 15360) {
        int u = t - 11264;
        int j = u / 64, k = u - j * 64;
        W2T[u] = f2bf(W2[k * 64 + j]);
    } else if (t < 17408) {
        int u = t - 15360;
        int j = u / 32, k = u - j * 32;
        W1T[u] = f2bf(W1[k * 64 + j]);
    }
}

// ---------------- layer-1 per-node GEMM (MFMA): hsc = (x@W1)*dinv, bf16 ----------------
__global__ __launch_bounds__(256) void k_nodemm32_mfma(const float* __restrict__ x, const short* __restrict__ W1T,
                                                       const float* __restrict__ dinv,
                                                       unsigned short* __restrict__ out, int n)
{
    const int tid = threadIdx.x;
    const int w = tid >> 6, lane = tid & 63, r = lane & 31, kg = lane >> 5;
    const int nb = blockIdx.x * 128 + w * 32;

    bf16x8 a0[2], a1[2];
#pragma unroll
    for (int t = 0; t < 2; ++t) {
        a0[t] = *(const bf16x8*)&W1T[r * 32 + t * 16 + kg * 8];
        a1[t] = *(const bf16x8*)&W1T[(r + 32) * 32 + t * 16 + kg * 8];
    }

    int row = nb + r;
    if (row >= n) row = n - 1;
    f32x16 acc0 = {0.f}, acc1 = {0.f};
#pragma unroll
    for (int t = 0; t < 2; ++t) {
        const float* xr = &x[(size_t)row * 32 + t * 16 + kg * 8];
        float4 lo = *(const float4*)xr;
        float4 hi = *(const float4*)(xr + 4);
        bf16x8 b;
        b[0] = f2bf(lo.x); b[1] = f2bf(lo.y); b[2] = f2bf(lo.z); b[3] = f2bf(lo.w);
        b[4] = f2bf(hi.x); b[5] = f2bf(hi.y); b[6] = f2bf(hi.z); b[7] = f2bf(hi.w);
        acc0 = __builtin_amdgcn_mfma_f32_32x32x16_bf16(a0[t], b, acc0, 0, 0, 0);
        acc1 = __builtin_amdgcn_mfma_f32_32x32x16_bf16(a1[t], b, acc1, 0, 0, 0);
    }

    const int node = nb + r;
    if (node < n) {
        const float dv = dinv[node];
#pragma unroll
        for (int q = 0; q < 4; ++q) {
            const int j0 = 8 * q + 4 * kg;
            short4 s0, s1;
            s0.x = f2bf(acc0[4 * q]     * dv); s0.y = f2bf(acc0[4 * q + 1] * dv);
            s0.z = f2bf(acc0[4 * q + 2] * dv); s0.w = f2bf(acc0[4 * q + 3] * dv);
            s1.x = f2bf(acc1[4 * q]     * dv); s1.y = f2bf(acc1[4 * q + 1] * dv);
            s1.z = f2bf(acc1[4 * q + 2] * dv); s1.w = f2bf(acc1[4 * q + 3] * dv);
            *(short4*)&out[(size_t)node * 64 + j0]      = s0;
            *(short4*)&out[(size_t)node * 64 + j0 + 32] = s1;
        }
    }
}

// ---------------- layer-2 per-node GEMM (MFMA): hsc2 = (h1@W2)*dinv, bf16 ----------------
__global__ __launch_bounds__(256) void k_nodemm64_mfma(const unsigned short* __restrict__ h1,
                                                       const short* __restrict__ W2T,
                                                       const float* __restrict__ dinv,
                                                       unsigned short* __restrict__ out, int n)
{
    const int tid = threadIdx.x;
    const int w = tid >> 6, lane = tid & 63, r = lane & 31, kg = lane >> 5;
    const int nb = blockIdx.x * 128 + w * 32;

    bf16x8 a0[4], a1[4];
#pragma unroll
    for (int t = 0; t < 4; ++t) {
        a0[t] = *(const bf16x8*)&W2T[r * 64 + t * 16 + kg * 8];
        a1[t] = *(const bf16x8*)&W2T[(r + 32) * 64 + t * 16 + kg * 8];
    }

    int row = nb + r;
    if (row >= n) row = n - 1;
    f32x16 acc0 = {0.f}, acc1 = {0.f};
#pragma unroll
    for (int t = 0; t < 4; ++t) {
        bf16x8 b = *(const bf16x8*)&h1[(size_t)row * 64 + t * 16 + kg * 8];
        acc0 = __builtin_amdgcn_mfma_f32_32x32x16_bf16(a0[t], b, acc0, 0, 0, 0);
        acc1 = __builtin_amdgcn_mfma_f32_32x32x16_bf16(a1[t], b, acc1, 0, 0, 0);
    }

    const int node = nb + r;
    if (node < n) {
        const float dv = dinv[node];
#pragma unroll
        for (int q = 0; q < 4; ++q) {
            const int j0 = 8 * q + 4 * kg;
            short4 s0, s1;
            s0.x = f2bf(acc0[4 * q]     * dv); s0.y = f2bf(acc0[4 * q + 1] * dv);
            s0.z = f2bf(acc0[4 * q + 2] * dv); s0.w = f2bf(acc0[4 * q + 3] * dv);
            s1.x = f2bf(acc1[4 * q]     * dv); s1.y = f2bf(acc1[4 * q + 1] * dv);
            s1.z = f2bf(acc1[4 * q + 2] * dv); s1.w = f2bf(acc1[4 * q + 3] * dv);
            *(short4*)&out[(size_t)node * 64 + j0]      = s0;
            *(short4*)&out[(size_t)node * 64 + j0 + 32] = s1;
        }
    }
}

// ---------------- aggregation (bf16) ----------------
template <int RELU>
__global__ __launch_bounds__(256) void k_agg_bf(const unsigned short* __restrict__ hsc,
                                                const float* __restrict__ dinv,
                                                const int* __restrict__ rs, const int* __restrict__ col,
                                                const float* __restrict__ bias,
                                                unsigned short* __restrict__ out, int n)
{
    const int tid = threadIdx.x;
    const int l   = tid & 31;
    const int v   = blockIdx.x * 8 + (tid >> 5);
    if (v >= n) return;

    float2 acc = bfp2f(*(const unsigned*)(hsc + (size_t)v * 64 + l * 2));   // self
    int i = rs[v];
    const int end = rs[v + 1];
    for (; i + 8 <= end; i += 8) {
        int c0 = col[i],     c1 = col[i + 1], c2 = col[i + 2], c3 = col[i + 3];
        int c4 = col[i + 4], c5 = col[i + 5], c6 = col[i + 6], c7 = col[i + 7];
        unsigned u0 = *(const unsigned*)(hsc + (size_t)c0 * 64 + l * 2);
        unsigned u1 = *(const unsigned*)(hsc + (size_t)c1 * 64 + l * 2);
        unsigned u2 = *(const unsigned*)(hsc + (size_t)c2 * 64 + l * 2);
        unsigned u3 = *(const unsigned*)(hsc + (size_t)c3 * 64 + l * 2);
        unsigned u4 = *(const unsigned*)(hsc + (size_t)c4 * 64 + l * 2);
        unsigned u5 = *(const unsigned*)(hsc + (size_t)c5 * 64 + l * 2);
        unsigned u6 = *(const unsigned*)(hsc + (size_t)c6 * 64 + l * 2);
        unsigned u7 = *(const unsigned*)(hsc + (size_t)c7 * 64 + l * 2);
        float2 a0 = bfp2f(u0), a1 = bfp2f(u1), a2 = bfp2f(u2), a3 = bfp2f(u3);
        float2 a4 = bfp2f(u4), a5 = bfp2f(u5), a6 = bfp2f(u6), a7 = bfp2f(u7);
        acc.x += (a0.x + a1.x) + (a2.x + a3.x) + (a4.x + a5.x) + (a6.x + a7.x);
        acc.y += (a0.y + a1.y) + (a2.y + a3.y) + (a4.y + a5.y) + (a6.y + a7.y);
    }
    for (; i + 4 <= end; i += 4) {
        int c0 = col[i], c1 = col[i + 1], c2 = col[i + 2], c3 = col[i + 3];
        unsigned u0 = *(const unsigned*)(hsc + (size_t)c0 * 64 + l * 2);
        unsigned u1 = *(const unsigned*)(hsc + (size_t)c1 * 64 + l * 2);
        unsigned u2 = *(const unsigned*)(hsc + (size_t)c2 * 64 + l * 2);
        unsigned u3 = *(const unsigned*)(hsc + (size_t)c3 * 64 + l * 2);
        float2 a0 = bfp2f(u0), a1 = bfp2f(u1), a2 = bfp2f(u2), a3 = bfp2f(u3);
        acc.x += (a0.x + a1.x) + (a2.x + a3.x);
        acc.y += (a0.y + a1.y) + (a2.y + a3.y);
    }
    for (; i < end; ++i) {
        float2 a = bfp2f(*(const unsigned*)(hsc + (size_t)col[i] * 64 + l * 2));
        acc.x += a.x; acc.y += a.y;
    }
    const float dv = dinv[v];
    float r0 = fmaf(dv, acc.x, bias[l * 2]);
    float r1 = fmaf(dv, acc.y, bias[l * 2 + 1]);
    if (RELU) { r0 = r0 > 0.f ? r0 : 0.f; r1 = r1 > 0.f ? r1 : 0.f; }
    unsigned o = (unsigned)(unsigned short)f2bf(r0) | ((unsigned)(unsigned short)f2bf(r1) << 16);
    *(unsigned*)(out + (size_t)v * 64 + l * 2) = o;
}

// ---------------- persistent-block MFMA edge MLP (LDS weights + LDS row slab) ----------------
#define SLAB 4608   // bytes per wave slab: 32 rows * 144 B (padded stride)

__global__ __launch_bounds__(256, 4) void k_edge_mlp_mfma(
    const unsigned short* __restrict__ h2bf, const float* __restrict__ eattr,
    const int* __restrict__ ei,
    const short* __restrict__ Wc1T, const float* __restrict__ bc1,
    const short* __restrict__ Wc2T, const float* __restrict__ bc2,
    float* __restrict__ out, int E, int ntiles)
{
    __shared__ int4 wlds4[22 * 64];      // 22528 B: weight register-image
    __shared__ int4 slab4[4 * SLAB / 16];// 18432 B: per-wave row slabs (total 40960 B)
    short* wlds = (short*)wlds4;
    char*  slab = (char*)slab4;

    const int tid = threadIdx.x;
    const int w = tid >> 6, lane = tid & 63, r = lane & 31, kg = lane >> 5;

    // ---- stage weight register-image into LDS (once per block) ----
    for (int id = tid; id < 1408; id += 256) {
        int f = id >> 6, l = id & 63, r2 = l & 31, kg2 = l >> 5;
        const short* src;
        if (f < 18) { int t = f >> 1, nt = f & 1; src = &Wc1T[(r2 + nt * 32) * 144 + t * 16 + kg2 * 8]; }
        else        { int t2 = f - 18;            src = &Wc2T[r2 * 64 + t2 * 16 + kg2 * 8]; }
        wlds4[id] = *(const int4*)src;
    }
    __syncthreads();

    char* myslab = slab + w * SLAB;
    short* hid = (short*)myslab;         // layer-1 output tile aliases the slab

    bf16x8 b2f[4];
#pragma unroll
    for (int t2 = 0; t2 < 4; ++t2) b2f[t2] = *(const bf16x8*)&wlds[((18 + t2) * 64 + lane) * 8];

    const float bias0 = bc1[r], bias1 = bc1[r + 32];
    const float bias2 = (r < 5) ? bc2[r] : 0.f;

    const int q  = lane & 3;    // staging: 16B chunk within 64B half
    const int sr = lane >> 2;   // staging: sub-row 0..15

    int tile = blockIdx.x;
    if (tile >= ntiles) return;
    long eb = (long)tile * 128 + w * 32;
    long ecl = eb + r; if (ecl >= E) ecl = E - 1;
    int ns = ei[ecl], nd = ei[E + ecl];

    while (true) {
        // attr loads issued early (lane's own edge row, 32 B)
        const float* arow = &eattr[(size_t)ecl * 16];
        float4 alo = *(const float4*)&arow[kg * 8];
        float4 ahi = *(const float4*)&arow[kg * 8 + 4];

        // ---- stage 32 src rows: full 64B-line gathers, 16 rows/instr ----
        int4 gv0, gv1, gv2, gv3;
        {
            int n0 = __shfl(ns, sr);        int n1 = __shfl(ns, 16 + sr);
            gv0 = *(const int4*)&h2bf[(size_t)n0 * 64 + q * 8];        // half 0
            gv1 = *(const int4*)&h2bf[(size_t)n1 * 64 + q * 8];
            gv2 = *(const int4*)&h2bf[(size_t)n0 * 64 + 32 + q * 8];   // half 1
            gv3 = *(const int4*)&h2bf[(size_t)n1 * 64 + 32 + q * 8];
        }
        *(int4*)(myslab + sr * 144 + q * 16)              = gv0;
        *(int4*)(myslab + (16 + sr) * 144 + q * 16)       = gv1;
        *(int4*)(myslab + sr * 144 + 64 + q * 16)         = gv2;
        *(int4*)(myslab + (16 + sr) * 144 + 64 + q * 16)  = gv3;

        // prefetch next tile's node ids
        const int ntile = tile + gridDim.x;
        const bool more = (ntile < ntiles);
        long eb2 = 0, ecl2 = 0; int ns2 = 0, nd2 = 0;
        if (more) {
            eb2 = (long)ntile * 128 + w * 32;
            ecl2 = eb2 + r; if (ecl2 >= E) ecl2 = E - 1;
            ns2 = ei[ecl2]; nd2 = ei[E + ecl2];
        }

        // ---- read src frags (linear-ish, slot-uniform), issue dst gathers ----
        bf16x8 avs0 = *(const bf16x8*)(myslab + r * 144 + (0 + kg) * 16);
        bf16x8 avs1 = *(const bf16x8*)(myslab + r * 144 + (2 + kg) * 16);
        bf16x8 avs2 = *(const bf16x8*)(myslab + r * 144 + (4 + kg) * 16);
        bf16x8 avs3 = *(const bf16x8*)(myslab + r * 144 + (6 + kg) * 16);
        {
            int n0 = __shfl(nd, sr);        int n1 = __shfl(nd, 16 + sr);
            gv0 = *(const int4*)&h2bf[(size_t)n0 * 64 + q * 8];
            gv1 = *(const int4*)&h2bf[(size_t)n1 * 64 + q * 8];
            gv2 = *(const int4*)&h2bf[(size_t)n0 * 64 + 32 + q * 8];
            gv3 = *(const int4*)&h2bf[(size_t)n1 * 64 + 32 + q * 8];
        }

        f32x16 acc0, acc1;
#pragma unroll
        for (int i = 0; i < 16; ++i) { acc0[i] = bias0; acc1[i] = bias1; }

        // MFMA k-steps 0..3 (src half), weights from LDS
#pragma unroll
        for (int t = 0; t < 4; ++t) {
            bf16x8 a = (t == 0) ? avs0 : (t == 1) ? avs1 : (t == 2) ? avs2 : avs3;
            bf16x8 w0 = *(const bf16x8*)&wlds[((t * 2 + 0) * 64 + lane) * 8];
            bf16x8 w1 = *(const bf16x8*)&wlds[((t * 2 + 1) * 64 + lane) * 8];
            acc0 = __builtin_amdgcn_mfma_f32_32x32x16_bf16(a, w0, acc0, 0, 0, 0);
            acc1 = __builtin_amdgcn_mfma_f32_32x32x16_bf16(a, w1, acc1, 0, 0, 0);
        }

        // stage dst rows (DS pipe is in-order per wave: writes follow src-frag reads)
        *(int4*)(myslab + sr * 144 + q * 16)              = gv0;
        *(int4*)(myslab + (16 + sr) * 144 + q * 16)       = gv1;
        *(int4*)(myslab + sr * 144 + 64 + q * 16)         = gv2;
        *(int4*)(myslab + (16 + sr) * 144 + 64 + q * 16)  = gv3;

        // MFMA k-steps 4..7 (dst half)
#pragma unroll
        for (int t = 0; t < 4; ++t) {
            bf16x8 a = *(const bf16x8*)(myslab + r * 144 + (2 * t + kg) * 16);
            bf16x8 w0 = *(const bf16x8*)&wlds[((8 + t * 2 + 0) * 64 + lane) * 8];
            bf16x8 w1 = *(const bf16x8*)&wlds[((8 + t * 2 + 1) * 64 + lane) * 8];
            acc0 = __builtin_amdgcn_mfma_f32_32x32x16_bf16(a, w0, acc0, 0, 0, 0);
            acc1 = __builtin_amdgcn_mfma_f32_32x32x16_bf16(a, w1, acc1, 0, 0, 0);
        }

        // attr k-step (t=8)
        {
            bf16x8 aa;
            aa[0] = f2bf(alo.x); aa[1] = f2bf(alo.y); aa[2] = f2bf(alo.z); aa[3] = f2bf(alo.w);
            aa[4] = f2bf(ahi.x); aa[5] = f2bf(ahi.y); aa[6] = f2bf(ahi.z); aa[7] = f2bf(ahi.w);
            bf16x8 w0 = *(const bf16x8*)&wlds[(16 * 64 + lane) * 8];
            bf16x8 w1 = *(const bf16x8*)&wlds[(17 * 64 + lane) * 8];
            acc0 = __builtin_amdgcn_mfma_f32_32x32x16_bf16(aa, w0, acc0, 0, 0, 0);
            acc1 = __builtin_amdgcn_mfma_f32_32x32x16_bf16(aa, w1, acc1, 0, 0, 0);
        }

        // epilogue 1: relu -> bf16 -> XOR-swizzled hid (first 4 KB of own slab)
#pragma unroll
        for (int reg = 0; reg < 16; ++reg) {
            const int row = (reg & 3) + 8 * (reg >> 2) + 4 * kg;
            const int sw  = (row & 7) << 4;
            float v0 = acc0[reg]; v0 = v0 > 0.f ? v0 : 0.f;
            float v1 = acc1[reg]; v1 = v1 > 0.f ? v1 : 0.f;
            hid[row * 64 + ((((r)      << 1) ^ sw) >> 1)] = f2bf(v0);
            hid[row * 64 + ((((r + 32) << 1) ^ sw) >> 1)] = f2bf(v1);
        }

        // layer 2
        const int sw2 = (r & 7) << 4;
        f32x16 acc2;
#pragma unroll
        for (int i = 0; i < 16; ++i) acc2[i] = bias2;
#pragma unroll
        for (int t2 = 0; t2 < 4; ++t2) {
            const int boff = (t2 * 32 + kg * 16) ^ sw2;
            bf16x8 a = *(const bf16x8*)((const char*)&hid[r * 64] + boff);
            acc2 = __builtin_amdgcn_mfma_f32_32x32x16_bf16(a, b2f[t2], acc2, 0, 0, 0);
        }

        // stores (edge order -> contiguous 640B block per wave)
#pragma unroll
        for (int reg = 0; reg < 16; ++reg) {
            const int row = (reg & 3) + 8 * (reg >> 2) + 4 * kg;
            const long eo = eb + row;
            if (r < 5 && eo < E) out[(size_t)eo * 5 + r] = acc2[reg];
        }

        if (!more) break;
        tile = ntile; eb = eb2; ecl = ecl2; ns = ns2; nd = nd2;
    }
}

extern "C" void kernel_launch(void* const* d_in, const int* in_sizes, int n_in,
                              void* d_out, int out_size, void* d_ws, size_t ws_size,
                              hipStream_t stream)
{
    const float* x     = (const float*)d_in[0];
    const int*   ei    = (const int*)d_in[1];
    const float* eattr = (const float*)d_in[2];
    const float* W1    = (const float*)d_in[3];
    const float* b1    = (const float*)d_in[4];
    const float* W2    = (const float*)d_in[5];
    const float* b2    = (const float*)d_in[6];
    const float* Wc1   = (const float*)d_in[7];
    const float* bc1   = (const float*)d_in[8];
    const float* Wc2   = (const float*)d_in[9];
    const float* bc2   = (const float*)d_in[10];
    float* outp = (float*)d_out;

    const int N = in_sizes[0] / 32;
    const int E = in_sizes[1] / 2;

    // ---- carve workspace ----
    size_t off = 0;
    char* base = (char*)d_ws;
    auto carve = [&](size_t bytes) -> void* {
        void* p = base + off;
        off += (bytes + 255) & ~(size_t)255;
        return p;
    };
    int*   degcnt = (int*)carve((size_t)2 * N * 4);
    int*   cursor = degcnt + N;
    float* dinv   = (float*)carve((size_t)N * 4);
    int*   rs     = (int*)carve((size_t)(N + 1) * 4);
    int*   bsum   = (int*)carve(512 * 4);
    int*   boff   = (int*)carve(512 * 4);
    int*   col    = (int*)carve((size_t)E * 4);
    unsigned short* hsc  = (unsigned short*)carve((size_t)N * 64 * 2);
    unsigned short* h1   = (unsigned short*)carve((size_t)N * 64 * 2);
    unsigned short* h2bf = h1;   // alias: h1 dead after nodemm64 reads it
    short* Wc1T   = (short*)carve(9216 * 2);
    short* Wc2T   = (short*)carve(2048 * 2);
    short* W2T    = (short*)carve(4096 * 2);
    short* W1T    = (short*)carve(2048 * 2);
    (void)ws_size; (void)n_in; (void)out_size;

    const int NB = (N + 255) / 256;
    const int EB = (E + 255) / 256;
    const int NA = (N + 7) / 8;          // agg: 8 nodes/block
    const int NM = (N + 127) / 128;      // nodemm MFMA: 128 nodes/block
    const int NT = (E + 127) / 128;      // edge-MLP tiles
    const int MG = NT < 1024 ? NT : 1024;

    hipMemsetAsync(degcnt, 0, (size_t)2 * N * 4, stream);

    k_prep<<<68, 256, 0, stream>>>(Wc1, Wc2, W2, W1, Wc1T, Wc2T, W2T, W1T);
    k_hist<<<EB, 256, 0, stream>>>(ei, degcnt, E);
    k_dinv_bsum<<<NB, 256, 0, stream>>>(degcnt, dinv, N, bsum);
    k_boff<<<1, 512, 0, stream>>>(bsum, NB, boff);
    k_rowstart<<<NB, 256, 0, stream>>>(degcnt, boff, rs, N, E);
    k_scatter<<<EB, 256, 0, stream>>>(ei, rs, cursor, col, E);

    // layer 1
    k_nodemm32_mfma<<<NM, 256, 0, stream>>>(x, W1T, dinv, hsc, N);
    k_agg_bf<1><<<NA, 256, 0, stream>>>(hsc, dinv, rs, col, b1, h1, N);
    // layer 2
    k_nodemm64_mfma<<<NM, 256, 0, stream>>>(h1, W2T, dinv, hsc, N);
    k_agg_bf<0><<<NA, 256, 0, stream>>>(hsc, dinv, rs, col, b2, h2bf, N);
    // edge MLP (persistent blocks, LDS weights + cooperative row staging)
    k_edge_mlp_mfma<<<MG, 256, 0, stream>>>(h2bf, eattr, ei, Wc1T, bc1, Wc2T, bc2, outp, E, NT);
}

// Round 9
// 394.179 us; speedup vs baseline: 1.4218x; 1.4218x over previous
//
#include <hip/hip_runtime.h>
#include <hip/hip_bf16.h>

// ---------------------------------------------------------------------------
// EdgeClassifier: 2x GCNConv + edge MLP. All node intermediates bf16.
//   CSR build -> nodemm32(MFMA) -> agg -> nodemm64(MFMA) -> agg
//   -> all-MFMA edge MLP with cooperative full-line row gathers:
//      * 32 node rows fetched as contiguous 64B segments by 4-lane groups
//        (2 line-requests/row instead of 4) into a chunk-major LDS slab
//      * slab: chunk*512 + row*16 -> contiguous DS writes/reads (no conflicts)
//      * src/dst in separate slab halves; hid aliases src half (in-order DS)
//      * weights reloaded per block from L1/L2 (R5-style, no VGPR cap/spill)
// ---------------------------------------------------------------------------

typedef __attribute__((ext_vector_type(8))) short  bf16x8;
typedef __attribute__((ext_vector_type(16))) float f32x16;

__device__ inline short f2bf(float f)
{
    union { float f; unsigned u; } v; v.f = f;
    unsigned r = v.u + 0x7fff + ((v.u >> 16) & 1);   // RNE
    return (short)(r >> 16);
}

__device__ inline float2 bfp2f(unsigned u)
{
    union { unsigned u; float f; } a, b;
    a.u = u << 16;
    b.u = u & 0xffff0000u;
    return make_float2(a.f, b.f);
}

// ---------------- CSR build ----------------
__global__ __launch_bounds__(256) void k_hist(const int* __restrict__ ei, int* __restrict__ degcnt, int E)
{
    int e = blockIdx.x * 256 + threadIdx.x;
    if (e < E) atomicAdd(&degcnt[ei[E + e]], 1);
}

__global__ __launch_bounds__(256) void k_dinv_bsum(const int* __restrict__ degcnt, float* __restrict__ dinv,
                                                   int n, int* __restrict__ bsum)
{
    __shared__ int s[256];
    int t = threadIdx.x;
    int i = blockIdx.x * 256 + t;
    int dg = (i < n) ? degcnt[i] : 0;
    if (i < n) dinv[i] = rsqrtf((float)(dg + 1));
    s[t] = dg;
    __syncthreads();
    for (int o = 128; o > 0; o >>= 1) {
        if (t < o) s[t] += s[t + o];
        __syncthreads();
    }
    if (t == 0) bsum[blockIdx.x] = s[0];
}

__global__ __launch_bounds__(512) void k_boff(const int* __restrict__ bsum, int nb, int* __restrict__ boff)
{
    __shared__ int s[512];
    int t = threadIdx.x;
    int v = (t < nb) ? bsum[t] : 0;
    s[t] = v;
    __syncthreads();
    for (int o = 1; o < 512; o <<= 1) {
        int a = (t >= o) ? s[t - o] : 0;
        __syncthreads();
        s[t] += a;
        __syncthreads();
    }
    if (t < nb) boff[t] = s[t] - v;
}

__global__ __launch_bounds__(256) void k_rowstart(const int* __restrict__ deg, const int* __restrict__ boff,
                                                  int* __restrict__ rs, int n, int total)
{
    __shared__ int s[256];
    int t = threadIdx.x;
    int i = blockIdx.x * 256 + t;
    int v = (i < n) ? deg[i] : 0;
    s[t] = v;
    __syncthreads();
    for (int o = 1; o < 256; o <<= 1) {
        int a = (t >= o) ? s[t - o] : 0;
        __syncthreads();
        s[t] += a;
        __syncthreads();
    }
    if (i < n) rs[i] = boff[blockIdx.x] + s[t] - v;
    if (i == 0) rs[n] = total;
}

__global__ __launch_bounds__(256) void k_scatter(const int* __restrict__ ei, const int* __restrict__ rs,
                                                 int* __restrict__ cursor, int* __restrict__ col, int E)
{
    int e = blockIdx.x * 256 + threadIdx.x;
    if (e < E) {
        int d = ei[E + e];
        int pos = atomicAdd(&cursor[d], 1);
        col[rs[d] + pos] = ei[e];
    }
}

// ---------------- weight prep (all bf16, transposed) ----------------
// Wc1T[64][144] | Wc2T[32][64] (class-padded) | W2T[64][64] | W1T[64][32]
__global__ __launch_bounds__(256) void k_prep(const float* __restrict__ Wc1, const float* __restrict__ Wc2,
                                              const float* __restrict__ W2, const float* __restrict__ W1,
                                              short* __restrict__ Wc1T, short* __restrict__ Wc2T,
                                              short* __restrict__ W2T, short* __restrict__ W1T)
{
    int t = blockIdx.x * 256 + threadIdx.x;
    if (t < 9216) {
        int j = t / 144, k = t - j * 144;
        Wc1T[t] = f2bf(Wc1[k * 64 + j]);
    } else if (t < 11264) {
        int u = t - 9216;
        int rr = u / 64, k = u - rr * 64;
        Wc2T[u] = (rr < 5) ? f2bf(Wc2[k * 5 + rr]) : (short)0;
    } else if (t < 15360) {
        int u = t - 11264;
        int j = u / 64, k = u - j * 64;
        W2T[u] = f2bf(W2[k * 64 + j]);
    } else if (t < 17408) {
        int u = t - 15360;
        int j = u / 32, k = u - j * 32;
        W1T[u] = f2bf(W1[k * 64 + j]);
    }
}

// ---------------- layer-1 per-node GEMM (MFMA): hsc = (x@W1)*dinv, bf16 ----------------
__global__ __launch_bounds__(256) void k_nodemm32_mfma(const float* __restrict__ x, const short* __restrict__ W1T,
                                                       const float* __restrict__ dinv,
                                                       unsigned short* __restrict__ out, int n)
{
    const int tid = threadIdx.x;
    const int w = tid >> 6, lane = tid & 63, r = lane & 31, kg = lane >> 5;
    const int nb = blockIdx.x * 128 + w * 32;

    bf16x8 a0[2], a1[2];
#pragma unroll
    for (int t = 0; t < 2; ++t) {
        a0[t] = *(const bf16x8*)&W1T[r * 32 + t * 16 + kg * 8];
        a1[t] = *(const bf16x8*)&W1T[(r + 32) * 32 + t * 16 + kg * 8];
    }

    int row = nb + r;
    if (row >= n) row = n - 1;
    f32x16 acc0 = {0.f}, acc1 = {0.f};
#pragma unroll
    for (int t = 0; t < 2; ++t) {
        const float* xr = &x[(size_t)row * 32 + t * 16 + kg * 8];
        float4 lo = *(const float4*)xr;
        float4 hi = *(const float4*)(xr + 4);
        bf16x8 b;
        b[0] = f2bf(lo.x); b[1] = f2bf(lo.y); b[2] = f2bf(lo.z); b[3] = f2bf(lo.w);
        b[4] = f2bf(hi.x); b[5] = f2bf(hi.y); b[6] = f2bf(hi.z); b[7] = f2bf(hi.w);
        acc0 = __builtin_amdgcn_mfma_f32_32x32x16_bf16(a0[t], b, acc0, 0, 0, 0);
        acc1 = __builtin_amdgcn_mfma_f32_32x32x16_bf16(a1[t], b, acc1, 0, 0, 0);
    }

    const int node = nb + r;
    if (node < n) {
        const float dv = dinv[node];
#pragma unroll
        for (int q = 0; q < 4; ++q) {
            const int j0 = 8 * q + 4 * kg;
            short4 s0, s1;
            s0.x = f2bf(acc0[4 * q]     * dv); s0.y = f2bf(acc0[4 * q + 1] * dv);
            s0.z = f2bf(acc0[4 * q + 2] * dv); s0.w = f2bf(acc0[4 * q + 3] * dv);
            s1.x = f2bf(acc1[4 * q]     * dv); s1.y = f2bf(acc1[4 * q + 1] * dv);
            s1.z = f2bf(acc1[4 * q + 2] * dv); s1.w = f2bf(acc1[4 * q + 3] * dv);
            *(short4*)&out[(size_t)node * 64 + j0]      = s0;
            *(short4*)&out[(size_t)node * 64 + j0 + 32] = s1;
        }
    }
}

// ---------------- layer-2 per-node GEMM (MFMA): hsc2 = (h1@W2)*dinv, bf16 ----------------
__global__ __launch_bounds__(256) void k_nodemm64_mfma(const unsigned short* __restrict__ h1,
                                                       const short* __restrict__ W2T,
                                                       const float* __restrict__ dinv,
                                                       unsigned short* __restrict__ out, int n)
{
    const int tid = threadIdx.x;
    const int w = tid >> 6, lane = tid & 63, r = lane & 31, kg = lane >> 5;
    const int nb = blockIdx.x * 128 + w * 32;

    bf16x8 a0[4], a1[4];
#pragma unroll
    for (int t = 0; t < 4; ++t) {
        a0[t] = *(const bf16x8*)&W2T[r * 64 + t * 16 + kg * 8];
        a1[t] = *(const bf16x8*)&W2T[(r + 32) * 64 + t * 16 + kg * 8];
    }

    int row = nb + r;
    if (row >= n) row = n - 1;
    f32x16 acc0 = {0.f}, acc1 = {0.f};
#pragma unroll
    for (int t = 0; t < 4; ++t) {
        bf16x8 b = *(const bf16x8*)&h1[(size_t)row * 64 + t * 16 + kg * 8];
        acc0 = __builtin_amdgcn_mfma_f32_32x32x16_bf16(a0[t], b, acc0, 0, 0, 0);
        acc1 = __builtin_amdgcn_mfma_f32_32x32x16_bf16(a1[t], b, acc1, 0, 0, 0);
    }

    const int node = nb + r;
    if (node < n) {
        const float dv = dinv[node];
#pragma unroll
        for (int q = 0; q < 4; ++q) {
            const int j0 = 8 * q + 4 * kg;
            short4 s0, s1;
            s0.x = f2bf(acc0[4 * q]     * dv); s0.y = f2bf(acc0[4 * q + 1] * dv);
            s0.z = f2bf(acc0[4 * q + 2] * dv); s0.w = f2bf(acc0[4 * q + 3] * dv);
            s1.x = f2bf(acc1[4 * q]     * dv); s1.y = f2bf(acc1[4 * q + 1] * dv);
            s1.z = f2bf(acc1[4 * q + 2] * dv); s1.w = f2bf(acc1[4 * q + 3] * dv);
            *(short4*)&out[(size_t)node * 64 + j0]      = s0;
            *(short4*)&out[(size_t)node * 64 + j0 + 32] = s1;
        }
    }
}

// ---------------- aggregation (bf16) ----------------
template <int RELU>
__global__ __launch_bounds__(256) void k_agg_bf(const unsigned short* __restrict__ hsc,
                                                const float* __restrict__ dinv,
                                                const int* __restrict__ rs, const int* __restrict__ col,
                                                const float* __restrict__ bias,
                                                unsigned short* __restrict__ out, int n)
{
    const int tid = threadIdx.x;
    const int l   = tid & 31;
    const int v   = blockIdx.x * 8 + (tid >> 5);
    if (v >= n) return;

    float2 acc = bfp2f(*(const unsigned*)(hsc + (size_t)v * 64 + l * 2));   // self
    int i = rs[v];
    const int end = rs[v + 1];
    for (; i + 8 <= end; i += 8) {
        int c0 = col[i],     c1 = col[i + 1], c2 = col[i + 2], c3 = col[i + 3];
        int c4 = col[i + 4], c5 = col[i + 5], c6 = col[i + 6], c7 = col[i + 7];
        unsigned u0 = *(const unsigned*)(hsc + (size_t)c0 * 64 + l * 2);
        unsigned u1 = *(const unsigned*)(hsc + (size_t)c1 * 64 + l * 2);
        unsigned u2 = *(const unsigned*)(hsc + (size_t)c2 * 64 + l * 2);
        unsigned u3 = *(const unsigned*)(hsc + (size_t)c3 * 64 + l * 2);
        unsigned u4 = *(const unsigned*)(hsc + (size_t)c4 * 64 + l * 2);
        unsigned u5 = *(const unsigned*)(hsc + (size_t)c5 * 64 + l * 2);
        unsigned u6 = *(const unsigned*)(hsc + (size_t)c6 * 64 + l * 2);
        unsigned u7 = *(const unsigned*)(hsc + (size_t)c7 * 64 + l * 2);
        float2 a0 = bfp2f(u0), a1 = bfp2f(u1), a2 = bfp2f(u2), a3 = bfp2f(u3);
        float2 a4 = bfp2f(u4), a5 = bfp2f(u5), a6 = bfp2f(u6), a7 = bfp2f(u7);
        acc.x += (a0.x + a1.x) + (a2.x + a3.x) + (a4.x + a5.x) + (a6.x + a7.x);
        acc.y += (a0.y + a1.y) + (a2.y + a3.y) + (a4.y + a5.y) + (a6.y + a7.y);
    }
    for (; i + 4 <= end; i += 4) {
        int c0 = col[i], c1 = col[i + 1], c2 = col[i + 2], c3 = col[i + 3];
        unsigned u0 = *(const unsigned*)(hsc + (size_t)c0 * 64 + l * 2);
        unsigned u1 = *(const unsigned*)(hsc + (size_t)c1 * 64 + l * 2);
        unsigned u2 = *(const unsigned*)(hsc + (size_t)c2 * 64 + l * 2);
        unsigned u3 = *(const unsigned*)(hsc + (size_t)c3 * 64 + l * 2);
        float2 a0 = bfp2f(u0), a1 = bfp2f(u1), a2 = bfp2f(u2), a3 = bfp2f(u3);
        acc.x += (a0.x + a1.x) + (a2.x + a3.x);
        acc.y += (a0.y + a1.y) + (a2.y + a3.y);
    }
    for (; i < end; ++i) {
        float2 a = bfp2f(*(const unsigned*)(hsc + (size_t)col[i] * 64 + l * 2));
        acc.x += a.x; acc.y += a.y;
    }
    const float dv = dinv[v];
    float r0 = fmaf(dv, acc.x, bias[l * 2]);
    float r1 = fmaf(dv, acc.y, bias[l * 2 + 1]);
    if (RELU) { r0 = r0 > 0.f ? r0 : 0.f; r1 = r1 > 0.f ? r1 : 0.f; }
    unsigned o = (unsigned)(unsigned short)f2bf(r0) | ((unsigned)(unsigned short)f2bf(r1) << 16);
    *(unsigned*)(out + (size_t)v * 64 + l * 2) = o;
}

// ---------------- MFMA edge MLP with cooperative full-line gathers ----------------
// Block = 256 thr = 4 waves; wave owns 32 edges; 8 KB slab per wave:
//   [0,4096)   src rows, chunk-major: byte = chunk*512 + row*16  (chunk 0..7)
//   [4096,8192) dst rows, same layout
// hid (layer-1 out, 4 KB) aliases the src half after it is consumed.
__global__ __launch_bounds__(256) void k_edge_mlp_mfma(
    const unsigned short* __restrict__ h2bf, const float* __restrict__ eattr,
    const int* __restrict__ ei,
    const short* __restrict__ Wc1T, const float* __restrict__ bc1,
    const short* __restrict__ Wc2T, const float* __restrict__ bc2,
    float* __restrict__ out, int E)
{
    __shared__ char slab[4 * 8192];   // 32 KB

    const int tid = threadIdx.x;
    const int w = tid >> 6, lane = tid & 63, r = lane & 31, kg = lane >> 5;
    const int q = lane & 3, sr = lane >> 2;   // coop-staging coords

    char* myslab = slab + w * 8192;
    short* hid = (short*)myslab;              // aliases src half

    const long eb = (long)blockIdx.x * 128 + w * 32;
    long ecl = eb + r; if (ecl >= E) ecl = E - 1;
    const int ns = ei[ecl];
    const int nd = ei[E + ecl];

    // attr (per-lane, coalesced-ish 32 B)
    const float* arow = &eattr[(size_t)ecl * 16];
    float4 alo = *(const float4*)&arow[kg * 8];
    float4 ahi = *(const float4*)&arow[kg * 8 + 4];

    // ---- cooperative gathers: 4-lane groups fetch contiguous 64 B per row ----
    {
        int n0 = __shfl(ns, sr);          // rows 0..15
        int n1 = __shfl(ns, 16 + sr);     // rows 16..31
        int m0 = __shfl(nd, sr);
        int m1 = __shfl(nd, 16 + sr);
        int4 s0 = *(const int4*)&h2bf[(size_t)n0 * 64 + q * 8];        // src chunk q
        int4 s1 = *(const int4*)&h2bf[(size_t)n0 * 64 + 32 + q * 8];   // src chunk 4+q
        int4 s2 = *(const int4*)&h2bf[(size_t)n1 * 64 + q * 8];
        int4 s3 = *(const int4*)&h2bf[(size_t)n1 * 64 + 32 + q * 8];
        int4 d0 = *(const int4*)&h2bf[(size_t)m0 * 64 + q * 8];
        int4 d1 = *(const int4*)&h2bf[(size_t)m0 * 64 + 32 + q * 8];
        int4 d2 = *(const int4*)&h2bf[(size_t)m1 * 64 + q * 8];
        int4 d3 = *(const int4*)&h2bf[(size_t)m1 * 64 + 32 + q * 8];
        *(int4*)(myslab + q * 512 + sr * 16)                     = s0;
        *(int4*)(myslab + (4 + q) * 512 + sr * 16)               = s1;
        *(int4*)(myslab + q * 512 + (16 + sr) * 16)              = s2;
        *(int4*)(myslab + (4 + q) * 512 + (16 + sr) * 16)        = s3;
        *(int4*)(myslab + 4096 + q * 512 + sr * 16)              = d0;
        *(int4*)(myslab + 4096 + (4 + q) * 512 + sr * 16)        = d1;
        *(int4*)(myslab + 4096 + q * 512 + (16 + sr) * 16)       = d2;
        *(int4*)(myslab + 4096 + (4 + q) * 512 + (16 + sr) * 16) = d3;
    }

    f32x16 acc0, acc1;
    const float bias0 = bc1[r], bias1 = bc1[r + 32];
#pragma unroll
    for (int i = 0; i < 16; ++i) { acc0[i] = bias0; acc1[i] = bias1; }

    // ---- layer-1 MFMA: src k-steps 0..3, dst k-steps 4..7, attr k-step 8 ----
#pragma unroll
    for (int t = 0; t < 4; ++t) {
        bf16x8 a  = *(const bf16x8*)(myslab + (2 * t + kg) * 512 + r * 16);
        bf16x8 w0 = *(const bf16x8*)&Wc1T[r * 144 + t * 16 + kg * 8];
        bf16x8 w1 = *(const bf16x8*)&Wc1T[(r + 32) * 144 + t * 16 + kg * 8];
        acc0 = __builtin_amdgcn_mfma_f32_32x32x16_bf16(a, w0, acc0, 0, 0, 0);
        acc1 = __builtin_amdgcn_mfma_f32_32x32x16_bf16(a, w1, acc1, 0, 0, 0);
    }
#pragma unroll
    for (int t = 0; t < 4; ++t) {
        bf16x8 a  = *(const bf16x8*)(myslab + 4096 + (2 * t + kg) * 512 + r * 16);
        bf16x8 w0 = *(const bf16x8*)&Wc1T[r * 144 + (4 + t) * 16 + kg * 8];
        bf16x8 w1 = *(const bf16x8*)&Wc1T[(r + 32) * 144 + (4 + t) * 16 + kg * 8];
        acc0 = __builtin_amdgcn_mfma_f32_32x32x16_bf16(a, w0, acc0, 0, 0, 0);
        acc1 = __builtin_amdgcn_mfma_f32_32x32x16_bf16(a, w1, acc1, 0, 0, 0);
    }
    {
        bf16x8 aa;
        aa[0] = f2bf(alo.x); aa[1] = f2bf(alo.y); aa[2] = f2bf(alo.z); aa[3] = f2bf(alo.w);
        aa[4] = f2bf(ahi.x); aa[5] = f2bf(ahi.y); aa[6] = f2bf(ahi.z); aa[7] = f2bf(ahi.w);
        bf16x8 w0 = *(const bf16x8*)&Wc1T[r * 144 + 128 + kg * 8];
        bf16x8 w1 = *(const bf16x8*)&Wc1T[(r + 32) * 144 + 128 + kg * 8];
        acc0 = __builtin_amdgcn_mfma_f32_32x32x16_bf16(aa, w0, acc0, 0, 0, 0);
        acc1 = __builtin_amdgcn_mfma_f32_32x32x16_bf16(aa, w1, acc1, 0, 0, 0);
    }

    // ---- epilogue 1: relu -> bf16 -> XOR-swizzled hid (src half, now dead) ----
#pragma unroll
    for (int reg = 0; reg < 16; ++reg) {
        const int row = (reg & 3) + 8 * (reg >> 2) + 4 * kg;
        const int sw  = (row & 7) << 4;
        float v0 = acc0[reg]; v0 = v0 > 0.f ? v0 : 0.f;
        float v1 = acc1[reg]; v1 = v1 > 0.f ? v1 : 0.f;
        hid[row * 64 + ((((r)      << 1) ^ sw) >> 1)] = f2bf(v0);
        hid[row * 64 + ((((r + 32) << 1) ^ sw) >> 1)] = f2bf(v1);
    }

    // ---- layer 2: hid @ Wc2T (4 k-steps) ----
    const int sw2 = (r & 7) << 4;
    const float bias2 = (r < 5) ? bc2[r] : 0.f;
    f32x16 acc2;
#pragma unroll
    for (int i = 0; i < 16; ++i) acc2[i] = bias2;
#pragma unroll
    for (int t2 = 0; t2 < 4; ++t2) {
        const int boff = (t2 * 32 + kg * 16) ^ sw2;
        bf16x8 a  = *(const bf16x8*)((const char*)&hid[r * 64] + boff);
        bf16x8 bw = *(const bf16x8*)&Wc2T[r * 64 + t2 * 16 + kg * 8];
        acc2 = __builtin_amdgcn_mfma_f32_32x32x16_bf16(a, bw, acc2, 0, 0, 0);
    }

    // ---- stores (edge order: contiguous 640 B per wave) ----
#pragma unroll
    for (int reg = 0; reg < 16; ++reg) {
        const int row = (reg & 3) + 8 * (reg >> 2) + 4 * kg;
        const long eo = eb + row;
        if (r < 5 && eo < E) out[(size_t)eo * 5 + r] = acc2[reg];
    }
}

extern "C" void kernel_launch(void* const* d_in, const int* in_sizes, int n_in,
                              void* d_out, int out_size, void* d_ws, size_t ws_size,
                              hipStream_t stream)
{
    const float* x     = (const float*)d_in[0];
    const int*   ei    = (const int*)d_in[1];
    const float* eattr = (const float*)d_in[2];
    const float* W1    = (const float*)d_in[3];
    const float* b1    = (const float*)d_in[4];
    const float* W2    = (const float*)d_in[5];
    const float* b2    = (const float*)d_in[6];
    const float* Wc1   = (const float*)d_in[7];
    const float* bc1   = (const float*)d_in[8];
    const float* Wc2   = (const float*)d_in[9];
    const float* bc2   = (const float*)d_in[10];
    float* outp = (float*)d_out;

    const int N = in_sizes[0] / 32;
    const int E = in_sizes[1] / 2;

    // ---- carve workspace (~34 MB) ----
    size_t off = 0;
    char* base = (char*)d_ws;
    auto carve = [&](size_t bytes) -> void* {
        void* p = base + off;
        off += (bytes + 255) & ~(size_t)255;
        return p;
    };
    int*   degcnt = (int*)carve((size_t)2 * N * 4);
    int*   cursor = degcnt + N;
    float* dinv   = (float*)carve((size_t)N * 4);
    int*   rs     = (int*)carve((size_t)(N + 1) * 4);
    int*   bsum   = (int*)carve(512 * 4);
    int*   boff   = (int*)carve(512 * 4);
    int*   col    = (int*)carve((size_t)E * 4);
    unsigned short* hsc  = (unsigned short*)carve((size_t)N * 64 * 2);
    unsigned short* h1   = (unsigned short*)carve((size_t)N * 64 * 2);
    unsigned short* h2bf = h1;   // alias: h1 dead after nodemm64 reads it
    short* Wc1T   = (short*)carve(9216 * 2);
    short* Wc2T   = (short*)carve(2048 * 2);
    short* W2T    = (short*)carve(4096 * 2);
    short* W1T    = (short*)carve(2048 * 2);
    (void)ws_size; (void)n_in; (void)out_size;

    const int NB = (N + 255) / 256;
    const int EB = (E + 255) / 256;
    const int NA = (N + 7) / 8;          // agg: 8 nodes/block
    const int NM = (N + 127) / 128;      // nodemm MFMA: 128 nodes/block
    const int NT = (E + 127) / 128;      // edge-MLP: 128 edges/block

    hipMemsetAsync(degcnt, 0, (size_t)2 * N * 4, stream);

    k_prep<<<68, 256, 0, stream>>>(Wc1, Wc2, W2, W1, Wc1T, Wc2T, W2T, W1T);
    k_hist<<<EB, 256, 0, stream>>>(ei, degcnt, E);
    k_dinv_bsum<<<NB, 256, 0, stream>>>(degcnt, dinv, N, bsum);
    k_boff<<<1, 512, 0, stream>>>(bsum, NB, boff);
    k_rowstart<<<NB, 256, 0, stream>>>(degcnt, boff, rs, N, E);
    k_scatter<<<EB, 256, 0, stream>>>(ei, rs, cursor, col, E);

    // layer 1
    k_nodemm32_mfma<<<NM, 256, 0, stream>>>(x, W1T, dinv, hsc, N);
    k_agg_bf<1><<<NA, 256, 0, stream>>>(hsc, dinv, rs, col, b1, h1, N);
    // layer 2
    k_nodemm64_mfma<<<NM, 256, 0, stream>>>(h1, W2T, dinv, hsc, N);
    k_agg_bf<0><<<NA, 256, 0, stream>>>(hsc, dinv, rs, col, b2, h2bf, N);
    // edge MLP (cooperative gathers)
    k_edge_mlp_mfma<<<NT, 256, 0, stream>>>(h2bf, eattr, ei, Wc1T, bc1, Wc2T, bc2, outp, E);
}